// Round 3
// baseline (841.412 us; speedup 1.0000x reference)
//
#include <hip/hip_runtime.h>
#include <hip/hip_bf16.h>
#include <cstdint>
#include <cstddef>

#define N_NODES 65536
#define N_EDGES 1048576
#define N_GRAPHS 128
#define NPG 512
#define IN_DIM 64
#define HID 128
#define BN_EPS 1e-5f

typedef __attribute__((ext_vector_type(8))) short bf16x8;
typedef __attribute__((ext_vector_type(4))) float f32x4;
typedef __attribute__((ext_vector_type(8))) unsigned short u16x8;

// ---- bf16 helpers (RNE, matches v_cvt) ----
__device__ inline unsigned short f2bf(float f) {
  unsigned u = __builtin_bit_cast(unsigned, f);
  u = u + 0x7fffu + ((u >> 16) & 1u);
  return (unsigned short)(u >> 16);
}
__device__ inline float bf2f(unsigned short h) {
  unsigned u = ((unsigned)h) << 16;
  return __builtin_bit_cast(float, u);
}
// RNE hi + RNE residual lo (used where lo magnitude matters for dropped cross-terms)
__device__ inline void split_bf(float v, unsigned short& hi, unsigned short& lo) {
  hi = f2bf(v);
  lo = f2bf(v - bf2f(hi));
}
// cheap split: truncated hi (1 shift) + RNE residual lo. hi+lo sum quality identical
// (|v-hi-lo| <~ 2^-17 |v|); saves ~3 VALU ops/value vs RNE-hi.
__device__ inline void split_bf_fast(float v, unsigned short& hi, unsigned short& lo) {
  unsigned u = __builtin_bit_cast(unsigned, v);
  hi = (unsigned short)(u >> 16);
  float r = v - __builtin_bit_cast(float, u & 0xffff0000u);
  lo = f2bf(r);
}

// ---------------- CSR build ----------------
__global__ __launch_bounds__(256) void hist_kernel(const int* __restrict__ dst,
                                                   int* __restrict__ deg) {
  int e = blockIdx.x * 256 + threadIdx.x;
  if (e < N_EDGES) atomicAdd(&deg[dst[e]], 1);
}

__global__ __launch_bounds__(256) void dis_kernel(const int* __restrict__ deg,
                                                  float* __restrict__ dis) {
  int n = blockIdx.x * 256 + threadIdx.x;
  if (n < N_NODES) dis[n] = 1.0f / sqrtf((float)deg[n] + 1.0f);
}

__global__ __launch_bounds__(1024) void scan_kernel(const int* __restrict__ deg,
                                                    int* __restrict__ offsets,
                                                    int* __restrict__ cursor) {
  __shared__ int sums[1024];
  int t = threadIdx.x;
  int base = t * 64;
  const int4* dp = (const int4*)(deg + base);
  int s = 0;
#pragma unroll
  for (int i = 0; i < 16; i++) {
    int4 v = dp[i];
    s += v.x + v.y + v.z + v.w;
  }
  sums[t] = s;
  __syncthreads();
  for (int off = 1; off < 1024; off <<= 1) {
    int v = (t >= off) ? sums[t - off] : 0;
    __syncthreads();
    sums[t] += v;
    __syncthreads();
  }
  int run = (t == 0) ? 0 : sums[t - 1];
#pragma unroll
  for (int i = 0; i < 16; i++) {
    int4 v = dp[i];
    int idx = base + i * 4;
    offsets[idx] = run; cursor[idx] = run; run += v.x;
    offsets[idx + 1] = run; cursor[idx + 1] = run; run += v.y;
    offsets[idx + 2] = run; cursor[idx + 2] = run; run += v.z;
    offsets[idx + 3] = run; cursor[idx + 3] = run; run += v.w;
  }
  if (t == 1023) offsets[N_NODES] = run;
}

__global__ __launch_bounds__(256) void fill_kernel(const int* __restrict__ src,
                                                   const int* __restrict__ dst,
                                                   int* __restrict__ cursor,
                                                   int* __restrict__ csr) {
  int e = blockIdx.x * 256 + threadIdx.x;
  if (e < N_EDGES) {
    int d = dst[e];
    int slot = atomicAdd(&cursor[d], 1);
    csr[slot] = src[e];
  }
}

// ---------------- aggregation (gather over CSR), chunk-4 prefetch, split-bf16 out ------
__global__ __launch_bounds__(256) void agg64_kernel(const float* __restrict__ x,
                                                    const float* __restrict__ dis,
                                                    const int* __restrict__ offsets,
                                                    const int* __restrict__ csr,
                                                    unsigned short* __restrict__ zhi,
                                                    unsigned short* __restrict__ zlo) {
  int node = blockIdx.x * 4 + (threadIdx.x >> 6);
  int lane = threadIdx.x & 63;
  float dn = dis[node];
  float acc = x[(size_t)node * 64 + lane] * dn * dn;
  int beg = offsets[node], end = offsets[node + 1];
  int k = beg;
  for (; k + 4 <= end; k += 4) {
    int s0 = csr[k], s1 = csr[k + 1], s2 = csr[k + 2], s3 = csr[k + 3];
    float w0 = dn * dis[s0], w1 = dn * dis[s1], w2 = dn * dis[s2], w3 = dn * dis[s3];
    float v0 = x[(size_t)s0 * 64 + lane];
    float v1 = x[(size_t)s1 * 64 + lane];
    float v2 = x[(size_t)s2 * 64 + lane];
    float v3 = x[(size_t)s3 * 64 + lane];
    acc = fmaf(w0, v0, acc);
    acc = fmaf(w1, v1, acc);
    acc = fmaf(w2, v2, acc);
    acc = fmaf(w3, v3, acc);
  }
  for (; k < end; k++) {
    int s = csr[k];
    acc = fmaf(dn * dis[s], x[(size_t)s * 64 + lane], acc);
  }
  unsigned short h_, l_;
  split_bf(acc, h_, l_);
  zhi[(size_t)node * 64 + lane] = h_;
  zlo[(size_t)node * 64 + lane] = l_;
}

__global__ __launch_bounds__(256) void agg128_kernel(const float* __restrict__ h,
                                                     const float* __restrict__ dis,
                                                     const int* __restrict__ offsets,
                                                     const int* __restrict__ csr,
                                                     unsigned short* __restrict__ zhi,
                                                     unsigned short* __restrict__ zlo) {
  int node = blockIdx.x * 4 + (threadIdx.x >> 6);
  int lane = threadIdx.x & 63;
  float dn = dis[node];
  float sn = dn * dn;
  const float* hr = h + (size_t)node * 128;
  float a0 = hr[lane] * sn;
  float a1 = hr[lane + 64] * sn;
  int beg = offsets[node], end = offsets[node + 1];
  int k = beg;
  for (; k + 4 <= end; k += 4) {
    int s0 = csr[k], s1 = csr[k + 1], s2 = csr[k + 2], s3 = csr[k + 3];
    float w0 = dn * dis[s0], w1 = dn * dis[s1], w2 = dn * dis[s2], w3 = dn * dis[s3];
    const float* p0 = h + (size_t)s0 * 128;
    const float* p1 = h + (size_t)s1 * 128;
    const float* p2 = h + (size_t)s2 * 128;
    const float* p3 = h + (size_t)s3 * 128;
    float u0 = p0[lane], d0 = p0[lane + 64];
    float u1 = p1[lane], d1 = p1[lane + 64];
    float u2 = p2[lane], d2 = p2[lane + 64];
    float u3 = p3[lane], d3 = p3[lane + 64];
    a0 = fmaf(w0, u0, a0); a1 = fmaf(w0, d0, a1);
    a0 = fmaf(w1, u1, a0); a1 = fmaf(w1, d1, a1);
    a0 = fmaf(w2, u2, a0); a1 = fmaf(w2, d2, a1);
    a0 = fmaf(w3, u3, a0); a1 = fmaf(w3, d3, a1);
  }
  for (; k < end; k++) {
    int s = csr[k];
    float w = dn * dis[s];
    const float* hs = h + (size_t)s * 128;
    a0 = fmaf(w, hs[lane], a0);
    a1 = fmaf(w, hs[lane + 64], a1);
  }
  unsigned short h0, l0, h1, l1;
  split_bf(a0, h0, l0);
  split_bf(a1, h1, l1);
  zhi[(size_t)node * 128 + lane] = h0;
  zlo[(size_t)node * 128 + lane] = l0;
  zhi[(size_t)node * 128 + lane + 64] = h1;
  zlo[(size_t)node * 128 + lane + 64] = l1;
}

// ---------------- weight prep: fp32 W -> bf16 hi/lo in b-fragment layout ----------------
template <bool TRANS>
__global__ __launch_bounds__(256) void wprep_kernel(const float* __restrict__ W, int K, int O,
                                                    unsigned short* __restrict__ hi,
                                                    unsigned short* __restrict__ lo) {
  int idx = blockIdx.x * 256 + threadIdx.x;
  int KC = K / 32;
  int total = (O / 16) * KC * 64;
  if (idx >= total) return;
  int lane = idx & 63;
  int rest = idx >> 6;
  int kc = rest % KC;
  int nt = rest / KC;
  int n = nt * 16 + (lane & 15);
  int kb = kc * 32 + (lane >> 4) * 8;
  unsigned short* hp = hi + (size_t)idx * 8;
  unsigned short* lp = lo + (size_t)idx * 8;
#pragma unroll
  for (int j = 0; j < 8; j++) {
    int k = kb + j;
    float v = TRANS ? W[(size_t)n * K + k] : W[(size_t)k * O + n];
    unsigned short h_, l_;
    split_bf(v, h_, l_);
    hp[j] = h_;
    lp[j] = l_;
  }
}

// ---------------- MFMA GEMM ----------------
// SPLIT_OUT: write hi/lo bf16. GROUPED: single output buffer, per-row stride 2*O u16,
// organized as (O/32) groups of 64 u16: [32 hi][32 lo] — keeps hi+lo of a 32-value
// head-slice in ONE 128B cache line for the attention kernel's staged reads.
template <int K, int O, bool DOBN, bool DORELU, bool SPLIT_OUT, bool GROUPED>
__global__ __launch_bounds__(256) void gemm_mfma(
    const unsigned short* __restrict__ Ahi, const unsigned short* __restrict__ Alo,
    const unsigned short* __restrict__ Whi, const unsigned short* __restrict__ Wlo,
    const float* __restrict__ bias,
    const float* __restrict__ gamma, const float* __restrict__ beta,
    const float* __restrict__ mean, const float* __restrict__ var,
    float* __restrict__ Cf, unsigned short* __restrict__ Chi,
    unsigned short* __restrict__ Clo) {
  constexpr int KC = K / 32;
  int wave = threadIdx.x >> 6;
  int lane = threadIdx.x & 63;
  int m0 = blockIdx.x * 128 + wave * 32;
  int o0 = blockIdx.y * 128;
  int mrow = lane & 15;
  int kseg = (lane >> 4) * 8;

  f32x4 acc[2][8];
#pragma unroll
  for (int mt = 0; mt < 2; mt++)
#pragma unroll
    for (int nt = 0; nt < 8; nt++) acc[mt][nt] = (f32x4)0.0f;

#pragma unroll
  for (int kc = 0; kc < KC; kc++) {
    bf16x8 ah[2], al[2];
#pragma unroll
    for (int mt = 0; mt < 2; mt++) {
      size_t aoff = (size_t)(m0 + mt * 16 + mrow) * K + kc * 32 + kseg;
      ah[mt] = *(const bf16x8*)(Ahi + aoff);
      al[mt] = *(const bf16x8*)(Alo + aoff);
    }
#pragma unroll
    for (int nt = 0; nt < 8; nt++) {
      size_t foff = (((size_t)(blockIdx.y * 8 + nt) * KC + kc) * 64 + lane) * 8;
      bf16x8 bh = *(const bf16x8*)(Whi + foff);
      bf16x8 bl = *(const bf16x8*)(Wlo + foff);
#pragma unroll
      for (int mt = 0; mt < 2; mt++) {
        acc[mt][nt] = __builtin_amdgcn_mfma_f32_16x16x32_bf16(ah[mt], bh, acc[mt][nt], 0, 0, 0);
        acc[mt][nt] = __builtin_amdgcn_mfma_f32_16x16x32_bf16(ah[mt], bl, acc[mt][nt], 0, 0, 0);
        acc[mt][nt] = __builtin_amdgcn_mfma_f32_16x16x32_bf16(al[mt], bh, acc[mt][nt], 0, 0, 0);
        acc[mt][nt] = __builtin_amdgcn_mfma_f32_16x16x32_bf16(al[mt], bl, acc[mt][nt], 0, 0, 0);
      }
    }
  }

  int ccol = lane & 15;
  int crow0 = (lane >> 4) * 4;
#pragma unroll
  for (int nt = 0; nt < 8; nt++) {
    int c = o0 + nt * 16 + ccol;
    float sc, cb;
    float b = bias[c];
    if (DOBN) {
      sc = gamma[c] * rsqrtf(var[c] + BN_EPS);
      cb = (b - mean[c]) * sc + beta[c];
    } else {
      sc = 1.0f;
      cb = b;
    }
#pragma unroll
    for (int mt = 0; mt < 2; mt++) {
#pragma unroll
      for (int r = 0; r < 4; r++) {
        float v = fmaf(acc[mt][nt][r], sc, cb);
        if (DORELU) v = fmaxf(v, 0.0f);
        size_t row = (size_t)(m0 + mt * 16 + crow0 + r);
        if (SPLIT_OUT) {
          unsigned short h_, l_;
          split_bf(v, h_, l_);
          if (GROUPED) {
            size_t base = row * (size_t)(2 * O) + (size_t)(((c >> 5) << 6) + (c & 31));
            Chi[base] = h_;
            Chi[base + 32] = l_;
          } else {
            Chi[row * O + c] = h_;
            Clo[row * O + c] = l_;
          }
        } else {
          Cf[row * O + c] = v;
        }
      }
    }
  }
}

// ---------------- key-norm max per (graph, head), grouped split input ----------------
__global__ __launch_bounds__(256) void knorm_kernel(const unsigned short* __restrict__ qvs,
                                                    float* __restrict__ kmax2) {
  int g = blockIdx.x >> 2;
  int h = blockIdx.x & 3;
  size_t gbase = (size_t)g * NPG;
  float best = 0.0f;
#pragma unroll
  for (int r = 0; r < 2; r++) {
    int j = r * 256 + threadIdx.x;
    size_t base = (gbase + j) * 768 + (size_t)(4 + h) * 64;  // K group for head h
    float s = 0.0f;
#pragma unroll
    for (int i = 0; i < 4; i++) {
      u16x8 hh = *(const u16x8*)(qvs + base + i * 8);
      u16x8 ll = *(const u16x8*)(qvs + base + 32 + i * 8);
#pragma unroll
      for (int jj = 0; jj < 8; jj++) {
        float v = bf2f(hh[jj]) + bf2f(ll[jj]);
        s = fmaf(v, v, s);
      }
    }
    best = fmaxf(best, s);
  }
#pragma unroll
  for (int off = 32; off >= 1; off >>= 1)
    best = fmaxf(best, __shfl_xor(best, off, 64));
  __shared__ float red[4];
  int wave = threadIdx.x >> 6;
  if ((threadIdx.x & 63) == 0) red[wave] = best;
  __syncthreads();
  if (threadIdx.x == 0) {
    float m = fmaxf(fmaxf(red[0], red[1]), fmaxf(red[2], red[3]));
    kmax2[blockIdx.x] = m;
  }
}

// ---------------- attention via MFMA (flash-style, single pass, C-S bound) --------------
// grid: 512 blocks = (graph, head); block 512 thr / 8 waves — each wave owns 64 of the
// graph-head's 512 queries, so K/V is staged ONCE per chunk for ALL queries (vs twice
// in the half-split variant) and the grid is exactly 2 sequential blocks/CU (balanced).
// QKV in GROUPED split layout: node row = 768 u16, 12 groups of [32 hi][32 lo].
// T14 staging fixed: next chunk's global loads are issued AFTER the second barrier
// (in flight during the whole compute phase) — the vmcnt(0) drain hipcc emits before
// each s_barrier then sees already-completed loads instead of serializing on them.
__global__ __launch_bounds__(512, 1) void attn_mfma_kernel(
    const unsigned short* __restrict__ qvs, const float* __restrict__ kmax2,
    unsigned short* __restrict__ ohi, unsigned short* __restrict__ olo) {
  int g = blockIdx.x >> 2;
  int h = blockIdx.x & 3;
  int t = threadIdx.x;
  int wave = t >> 6;
  int lane = t & 63;
  int quad = lane >> 4;
  int l15 = lane & 15;
  size_t gbase = (size_t)g * NPG;
  int qb = wave * 64;

  const float cf = 0.17677669529663687f * 1.4426950408889634f;  // scale*log2(e)

  __shared__ unsigned short Kh[32][40], Kl[32][40];   // [key][dim], 80B rows (16B-aligned)
  __shared__ unsigned short Vh[33][40], Vl[33][40];   // [dim][key] transposed; Vh row 32=ones
  __shared__ char wbuf[8][10240] __attribute__((aligned(16)));  // per-wave P / O-transpose

  unsigned short* Ph = (unsigned short*)wbuf[wave];        // [64][40] bf16
  unsigned short* Pl = Ph + 64 * 40;                       // [64][40] bf16
  float* Ot = (float*)wbuf[wave];                          // [64][36] f32 (epilogue/qn)

  // ---- Q fragments: direct pre-split loads + |q|^2 (reconstructed = what MFMA sees) ----
  bf16x8 qh[4], ql[4];
  float qn2p[4];
#pragma unroll
  for (int mt = 0; mt < 4; mt++) {
    size_t qoff = (gbase + qb + mt * 16 + l15) * 768 + (size_t)h * 64 + quad * 8;
    u16x8 hh = *(const u16x8*)(qvs + qoff);
    u16x8 ll = *(const u16x8*)(qvs + qoff + 32);
    qh[mt] = __builtin_bit_cast(bf16x8, hh);
    ql[mt] = __builtin_bit_cast(bf16x8, ll);
    float s = 0.0f;
#pragma unroll
    for (int j = 0; j < 8; j++) {
      float v = bf2f(hh[j]) + bf2f(ll[j]);
      s = fmaf(v, v, s);
    }
    s += __shfl_xor(s, 16);
    s += __shfl_xor(s, 32);
    qn2p[mt] = s;  // full |q|^2 for query mt*16 + l15
  }
  // exchange |q|^2 so each lane gets the bound for its C-layout rows
  if (quad == 0) {
#pragma unroll
    for (int mt = 0; mt < 4; mt++) Ot[mt * 16 + l15] = qn2p[mt];
  }
  float km2 = kmax2[g * 4 + h];
  float Mq[4][4];
#pragma unroll
  for (int mt = 0; mt < 4; mt++)
#pragma unroll
    for (int r = 0; r < 4; r++)
      Mq[mt][r] = cf * sqrtf(Ot[mt * 16 + quad * 4 + r] * km2);

  f32x4 Oa[4][3];
#pragma unroll
  for (int mt = 0; mt < 4; mt++)
#pragma unroll
    for (int nt = 0; nt < 3; nt++) Oa[mt][nt] = (f32x4)0.0f;

  // ones row for the l-column (dv=32): constant, write ONCE
  if (t >= 64 && t < 68) {
    int i = t - 64;
    u16x8 ones;
#pragma unroll
    for (int j = 0; j < 8; j++) ones[j] = 0x3F80;
    *(u16x8*)&Vh[32][i * 8] = ones;
  }

  // staging roles: threads 256-383 stage K (32 keys x 4 dim-segments);
  // threads 0-63 stage V^T (8 key-blocks x 8 dim-blocks)
  bool isK = (t >= 256 && t < 384);
  bool isV = (t < 64);
  u16x8 kreg_h, kreg_l;
  ushort4 vreg_h[4], vreg_l[4];
  int kkey = 0, kds = 0, vkeyb = 0, vdvb = 0;
  if (isK) {
    int t2 = t - 256;
    kkey = t2 >> 2;
    kds = (t2 & 3) * 8;
  } else if (isV) {
    vkeyb = (t & 7) * 4;
    vdvb = (t >> 3) * 4;
  }

  auto load_chunk = [&](int c) {
    if (isK) {
      size_t ko = (gbase + (size_t)(c * 32 + kkey)) * 768 + (size_t)(4 + h) * 64 + kds;
      kreg_h = *(const u16x8*)(qvs + ko);
      kreg_l = *(const u16x8*)(qvs + ko + 32);
    } else if (isV) {
#pragma unroll
      for (int r = 0; r < 4; r++) {
        size_t vo = (gbase + (size_t)(c * 32 + vkeyb + r)) * 768 + (size_t)(8 + h) * 64 + vdvb;
        vreg_h[r] = *(const ushort4*)(qvs + vo);
        vreg_l[r] = *(const ushort4*)(qvs + vo + 32);
      }
    }
  };

  load_chunk(0);  // prologue prefetch

  for (int c = 0; c < 16; c++) {
    __syncthreads();  // previous chunk's K/V LDS reads complete (loads long done)
    // ---- LDS write of prefetched chunk c ----
    if (isK) {
      *(u16x8*)&Kh[kkey][kds] = kreg_h;
      *(u16x8*)&Kl[kkey][kds] = kreg_l;
    } else if (isV) {
      unsigned short ha[4][4], la[4][4];
#pragma unroll
      for (int r = 0; r < 4; r++) {
        *(ushort4*)&ha[r][0] = vreg_h[r];
        *(ushort4*)&la[r][0] = vreg_l[r];
      }
#pragma unroll
      for (int c2 = 0; c2 < 4; c2++) {
        ushort4 hv, lv;
        hv.x = ha[0][c2]; hv.y = ha[1][c2]; hv.z = ha[2][c2]; hv.w = ha[3][c2];
        lv.x = la[0][c2]; lv.y = la[1][c2]; lv.z = la[2][c2]; lv.w = la[3][c2];
        *(ushort4*)&Vh[vdvb + c2][vkeyb] = hv;
        *(ushort4*)&Vl[vdvb + c2][vkeyb] = lv;
      }
    }
    __syncthreads();
    // ---- issue next chunk's loads NOW: in flight during the whole compute phase ----
    if (c < 15) load_chunk(c + 1);

    // ---- QK^T -> S -> P (scale folded into fma; cheap trunc-split; store to LDS) ----
#pragma unroll
    for (int nt = 0; nt < 2; nt++) {
      bf16x8 bkh = *(const bf16x8*)&Kh[nt * 16 + l15][quad * 8];
      bf16x8 bkl = *(const bf16x8*)&Kl[nt * 16 + l15][quad * 8];
#pragma unroll
      for (int mt = 0; mt < 4; mt++) {
        f32x4 S = (f32x4)0.0f;
        S = __builtin_amdgcn_mfma_f32_16x16x32_bf16(qh[mt], bkh, S, 0, 0, 0);
        S = __builtin_amdgcn_mfma_f32_16x16x32_bf16(qh[mt], bkl, S, 0, 0, 0);
        S = __builtin_amdgcn_mfma_f32_16x16x32_bf16(ql[mt], bkh, S, 0, 0, 0);
        S = __builtin_amdgcn_mfma_f32_16x16x32_bf16(ql[mt], bkl, S, 0, 0, 0);
#pragma unroll
        for (int r = 0; r < 4; r++) {
          float p = __builtin_exp2f(fmaf(S[r], cf, -Mq[mt][r]));
          unsigned short hi_, lo_;
          split_bf_fast(p, hi_, lo_);
          int row = mt * 16 + quad * 4 + r;
          Ph[row * 40 + nt * 16 + l15] = hi_;
          Pl[row * 40 + nt * 16 + l15] = lo_;
        }
      }
    }
    // ---- PV: P A-frags x V^T B-frags ----
    bf16x8 pah[4], pal[4];
#pragma unroll
    for (int mt = 0; mt < 4; mt++) {
      pah[mt] = *(const bf16x8*)&Ph[(mt * 16 + l15) * 40 + quad * 8];
      pal[mt] = *(const bf16x8*)&Pl[(mt * 16 + l15) * 40 + quad * 8];
    }
#pragma unroll
    for (int nt = 0; nt < 3; nt++) {
      bf16x8 bvh = *(const bf16x8*)&Vh[nt * 16 + l15][quad * 8];
      if (nt < 2) {
        bf16x8 bvl = *(const bf16x8*)&Vl[nt * 16 + l15][quad * 8];
#pragma unroll
        for (int mt = 0; mt < 4; mt++) {
          Oa[mt][nt] = __builtin_amdgcn_mfma_f32_16x16x32_bf16(pah[mt], bvh, Oa[mt][nt], 0, 0, 0);
          Oa[mt][nt] = __builtin_amdgcn_mfma_f32_16x16x32_bf16(pah[mt], bvl, Oa[mt][nt], 0, 0, 0);
          Oa[mt][nt] = __builtin_amdgcn_mfma_f32_16x16x32_bf16(pal[mt], bvh, Oa[mt][nt], 0, 0, 0);
        }
      } else {
#pragma unroll
        for (int mt = 0; mt < 4; mt++) {
          Oa[mt][nt] = __builtin_amdgcn_mfma_f32_16x16x32_bf16(pah[mt], bvh, Oa[mt][nt], 0, 0, 0);
          Oa[mt][nt] = __builtin_amdgcn_mfma_f32_16x16x32_bf16(pal[mt], bvh, Oa[mt][nt], 0, 0, 0);
        }
      }
    }
  }

  // ---- epilogue: transpose O through per-wave LDS, normalize, split-bf16 store ----
  // (per-wave buffer; wave-lockstep ds ordering makes this barrier-free)
#pragma unroll
  for (int mt = 0; mt < 4; mt++) {
#pragma unroll
    for (int r = 0; r < 4; r++) {
      int row = mt * 16 + quad * 4 + r;
      Ot[row * 36 + l15] = Oa[mt][0][r];
      Ot[row * 36 + 16 + l15] = Oa[mt][1][r];
      if (l15 == 0) Ot[row * 36 + 32] = Oa[mt][2][r];  // l = ones-column
    }
  }
  {
    int row = lane;  // wave's query row
    float inv = 1.0f / Ot[row * 36 + 32];
    size_t node = gbase + qb + row;
    u16x8 vh, vl;
#pragma unroll
    for (int seg = 0; seg < 4; seg++) {
#pragma unroll
      for (int j = 0; j < 8; j++) {
        unsigned short hi_, lo_;
        split_bf_fast(Ot[row * 36 + seg * 8 + j] * inv, hi_, lo_);
        vh[j] = hi_;
        vl[j] = lo_;
      }
      *(u16x8*)(ohi + node * 128 + h * 32 + seg * 8) = vh;
      *(u16x8*)(olo + node * 128 + h * 32 + seg * 8) = vl;
    }
  }
}

// ---------------- mean pool: 4 partial blocks per graph + atomic combine ----------------
__global__ __launch_bounds__(128) void pool_kernel(const float* __restrict__ fin,
                                                   float* __restrict__ emb) {
  int g = blockIdx.x >> 2;
  int q = blockIdx.x & 3;
  int c = threadIdx.x;
  const float* p = fin + ((size_t)g * NPG + (size_t)q * 128) * HID + c;
  float s = 0.0f;
#pragma unroll 4
  for (int i = 0; i < 128; i++) s += p[(size_t)i * HID];
  atomicAdd(&emb[g * HID + c], s * (1.0f / NPG));
}

extern "C" void kernel_launch(void* const* d_in, const int* in_sizes, int n_in,
                              void* d_out, int out_size, void* d_ws, size_t ws_size,
                              hipStream_t stream) {
  (void)in_sizes; (void)n_in; (void)out_size; (void)ws_size;
  const float* x          = (const float*)d_in[0];
  const float* W0         = (const float*)d_in[1];
  const float* b0         = (const float*)d_in[2];
  const float* Wh         = (const float*)d_in[3];
  const float* bh         = (const float*)d_in[4];
  const float* bn_gamma   = (const float*)d_in[5];
  const float* bn_beta    = (const float*)d_in[6];
  const float* bn_mean    = (const float*)d_in[7];
  const float* bn_var     = (const float*)d_in[8];
  const float* attn_in_w  = (const float*)d_in[9];
  const float* attn_in_b  = (const float*)d_in[10];
  const float* attn_out_w = (const float*)d_in[11];
  const float* attn_out_b = (const float*)d_in[12];
  const int* edge_index   = (const int*)d_in[13];
  const int* src = edge_index;
  const int* dst = edge_index + N_EDGES;

  char* ws = (char*)d_ws;
  size_t off = 0;
  auto alloc = [&](size_t bytes) -> void* {
    void* p = ws + off;
    off += (bytes + 255) & ~(size_t)255;
    return p;
  };
  int*   deg     = (int*)alloc((size_t)N_NODES * 4);
  int*   offsets = (int*)alloc((size_t)(N_NODES + 1) * 4);
  int*   cursor  = (int*)alloc((size_t)N_NODES * 4);
  int*   csr     = (int*)alloc((size_t)N_EDGES * 4);
  float* dis     = (float*)alloc((size_t)N_NODES * 4);
  float* bufA    = (float*)alloc((size_t)N_NODES * HID * 4);   // h fp32; later f_hi/f_lo
  unsigned short* zhi = (unsigned short*)alloc((size_t)N_NODES * HID * 2);  // also o_hi
  unsigned short* zlo = (unsigned short*)alloc((size_t)N_NODES * HID * 2);  // also o_lo
  unsigned short* qvs = (unsigned short*)alloc((size_t)N_NODES * 768 * 2);  // qkv grouped hi/lo
  float* kmax2   = (float*)alloc((size_t)N_GRAPHS * 4 * 4);
  unsigned short* w0h = (unsigned short*)alloc(8192 * 2);
  unsigned short* w0l = (unsigned short*)alloc(8192 * 2);
  unsigned short* whh[3], *whl[3];
  for (int i = 0; i < 3; i++) {
    whh[i] = (unsigned short*)alloc(16384 * 2);
    whl[i] = (unsigned short*)alloc(16384 * 2);
  }
  unsigned short* wqh = (unsigned short*)alloc(49152 * 2);
  unsigned short* wql = (unsigned short*)alloc(49152 * 2);
  unsigned short* woh = (unsigned short*)alloc(16384 * 2);
  unsigned short* wol = (unsigned short*)alloc(16384 * 2);

  unsigned short* fhi = (unsigned short*)bufA;
  unsigned short* flo = fhi + (size_t)N_NODES * HID;

  float* fin = (float*)d_out;                       // [N, HID]
  float* emb = fin + (size_t)N_NODES * HID;         // [G, HID]

  hipMemsetAsync(deg, 0, (size_t)N_NODES * 4, stream);
  hipMemsetAsync(emb, 0, (size_t)N_GRAPHS * HID * 4, stream);
  hist_kernel<<<N_EDGES / 256, 256, 0, stream>>>(dst, deg);
  dis_kernel<<<N_NODES / 256, 256, 0, stream>>>(deg, dis);
  scan_kernel<<<1, 1024, 0, stream>>>(deg, offsets, cursor);
  fill_kernel<<<N_EDGES / 256, 256, 0, stream>>>(src, dst, cursor, csr);

  wprep_kernel<false><<<4, 256, 0, stream>>>(W0, 64, 128, w0h, w0l);
  for (int i = 0; i < 3; i++)
    wprep_kernel<false><<<8, 256, 0, stream>>>(Wh + (size_t)i * HID * HID, 128, 128,
                                               whh[i], whl[i]);
  wprep_kernel<true><<<24, 256, 0, stream>>>(attn_in_w, 128, 384, wqh, wql);
  wprep_kernel<true><<<8, 256, 0, stream>>>(attn_out_w, 128, 128, woh, wol);

  dim3 ggrid(N_NODES / 128, 1);
  agg64_kernel<<<N_NODES / 4, 256, 0, stream>>>(x, dis, offsets, csr, zhi, zlo);
  gemm_mfma<64, 128, true, true, false, false><<<ggrid, 256, 0, stream>>>(
      zhi, zlo, w0h, w0l, b0, bn_gamma, bn_beta, bn_mean, bn_var, bufA, nullptr, nullptr);
  for (int L = 0; L < 2; L++) {
    agg128_kernel<<<N_NODES / 4, 256, 0, stream>>>(bufA, dis, offsets, csr, zhi, zlo);
    gemm_mfma<128, 128, true, true, false, false><<<ggrid, 256, 0, stream>>>(
        zhi, zlo, whh[L], whl[L], bh + (size_t)L * HID,
        bn_gamma + (size_t)(L + 1) * HID, bn_beta + (size_t)(L + 1) * HID,
        bn_mean + (size_t)(L + 1) * HID, bn_var + (size_t)(L + 1) * HID,
        bufA, nullptr, nullptr);
  }
  agg128_kernel<<<N_NODES / 4, 256, 0, stream>>>(bufA, dis, offsets, csr, zhi, zlo);
  gemm_mfma<128, 128, true, true, true, false><<<ggrid, 256, 0, stream>>>(
      zhi, zlo, whh[2], whl[2], bh + (size_t)2 * HID,
      bn_gamma + (size_t)3 * HID, bn_beta + (size_t)3 * HID,
      bn_mean + (size_t)3 * HID, bn_var + (size_t)3 * HID,
      nullptr, fhi, flo);
  dim3 qgrid(N_NODES / 128, 3);
  gemm_mfma<128, 384, false, false, true, true><<<qgrid, 256, 0, stream>>>(
      fhi, flo, wqh, wql, attn_in_b, nullptr, nullptr, nullptr, nullptr,
      nullptr, qvs, nullptr);
  knorm_kernel<<<N_GRAPHS * 4, 256, 0, stream>>>(qvs, kmax2);
  attn_mfma_kernel<<<N_GRAPHS * 4, 512, 0, stream>>>(qvs, kmax2, zhi, zlo);
  gemm_mfma<128, 128, false, false, false, false><<<ggrid, 256, 0, stream>>>(
      zhi, zlo, woh, wol, attn_out_b, nullptr, nullptr, nullptr, nullptr,
      fin, nullptr, nullptr);
  pool_kernel<<<N_GRAPHS * 4, 128, 0, stream>>>(fin, emb);
}

// Round 4
// 823.103 us; speedup vs baseline: 1.0222x; 1.0222x over previous
//
#include <hip/hip_runtime.h>
#include <hip/hip_bf16.h>
#include <cstdint>
#include <cstddef>

#define N_NODES 65536
#define N_EDGES 1048576
#define N_GRAPHS 128
#define NPG 512
#define IN_DIM 64
#define HID 128
#define BN_EPS 1e-5f

typedef __attribute__((ext_vector_type(8))) short bf16x8;
typedef __attribute__((ext_vector_type(4))) float f32x4;
typedef __attribute__((ext_vector_type(8))) unsigned short u16x8;

// ---- bf16 helpers (RNE, matches v_cvt) ----
__device__ inline unsigned short f2bf(float f) {
  unsigned u = __builtin_bit_cast(unsigned, f);
  u = u + 0x7fffu + ((u >> 16) & 1u);
  return (unsigned short)(u >> 16);
}
__device__ inline float bf2f(unsigned short h) {
  unsigned u = ((unsigned)h) << 16;
  return __builtin_bit_cast(float, u);
}
// RNE hi + RNE residual lo (used where lo magnitude matters for dropped cross-terms)
__device__ inline void split_bf(float v, unsigned short& hi, unsigned short& lo) {
  hi = f2bf(v);
  lo = f2bf(v - bf2f(hi));
}
// cheap split: truncated hi (1 shift) + RNE residual lo. hi+lo sum quality identical
// (|v-hi-lo| <~ 2^-17 |v|); saves ~3 VALU ops/value vs RNE-hi.
__device__ inline void split_bf_fast(float v, unsigned short& hi, unsigned short& lo) {
  unsigned u = __builtin_bit_cast(unsigned, v);
  hi = (unsigned short)(u >> 16);
  float r = v - __builtin_bit_cast(float, u & 0xffff0000u);
  lo = f2bf(r);
}

// ---------------- CSR build ----------------
__global__ __launch_bounds__(256) void hist_kernel(const int* __restrict__ dst,
                                                   int* __restrict__ deg) {
  int e = blockIdx.x * 256 + threadIdx.x;
  if (e < N_EDGES) atomicAdd(&deg[dst[e]], 1);
}

__global__ __launch_bounds__(256) void dis_kernel(const int* __restrict__ deg,
                                                  float* __restrict__ dis) {
  int n = blockIdx.x * 256 + threadIdx.x;
  if (n < N_NODES) dis[n] = 1.0f / sqrtf((float)deg[n] + 1.0f);
}

__global__ __launch_bounds__(1024) void scan_kernel(const int* __restrict__ deg,
                                                    int* __restrict__ offsets,
                                                    int* __restrict__ cursor) {
  __shared__ int sums[1024];
  int t = threadIdx.x;
  int base = t * 64;
  const int4* dp = (const int4*)(deg + base);
  int s = 0;
#pragma unroll
  for (int i = 0; i < 16; i++) {
    int4 v = dp[i];
    s += v.x + v.y + v.z + v.w;
  }
  sums[t] = s;
  __syncthreads();
  for (int off = 1; off < 1024; off <<= 1) {
    int v = (t >= off) ? sums[t - off] : 0;
    __syncthreads();
    sums[t] += v;
    __syncthreads();
  }
  int run = (t == 0) ? 0 : sums[t - 1];
#pragma unroll
  for (int i = 0; i < 16; i++) {
    int4 v = dp[i];
    int idx = base + i * 4;
    offsets[idx] = run; cursor[idx] = run; run += v.x;
    offsets[idx + 1] = run; cursor[idx + 1] = run; run += v.y;
    offsets[idx + 2] = run; cursor[idx + 2] = run; run += v.z;
    offsets[idx + 3] = run; cursor[idx + 3] = run; run += v.w;
  }
  if (t == 1023) offsets[N_NODES] = run;
}

__global__ __launch_bounds__(256) void fill_kernel(const int* __restrict__ src,
                                                   const int* __restrict__ dst,
                                                   int* __restrict__ cursor,
                                                   int* __restrict__ csr) {
  int e = blockIdx.x * 256 + threadIdx.x;
  if (e < N_EDGES) {
    int d = dst[e];
    int slot = atomicAdd(&cursor[d], 1);
    csr[slot] = src[e];
  }
}

// ---------------- aggregation (gather over CSR), chunk-4 prefetch, split-bf16 out ------
__global__ __launch_bounds__(256) void agg64_kernel(const float* __restrict__ x,
                                                    const float* __restrict__ dis,
                                                    const int* __restrict__ offsets,
                                                    const int* __restrict__ csr,
                                                    unsigned short* __restrict__ zhi,
                                                    unsigned short* __restrict__ zlo) {
  int node = blockIdx.x * 4 + (threadIdx.x >> 6);
  int lane = threadIdx.x & 63;
  float dn = dis[node];
  float acc = x[(size_t)node * 64 + lane] * dn * dn;
  int beg = offsets[node], end = offsets[node + 1];
  int k = beg;
  for (; k + 4 <= end; k += 4) {
    int s0 = csr[k], s1 = csr[k + 1], s2 = csr[k + 2], s3 = csr[k + 3];
    float w0 = dn * dis[s0], w1 = dn * dis[s1], w2 = dn * dis[s2], w3 = dn * dis[s3];
    float v0 = x[(size_t)s0 * 64 + lane];
    float v1 = x[(size_t)s1 * 64 + lane];
    float v2 = x[(size_t)s2 * 64 + lane];
    float v3 = x[(size_t)s3 * 64 + lane];
    acc = fmaf(w0, v0, acc);
    acc = fmaf(w1, v1, acc);
    acc = fmaf(w2, v2, acc);
    acc = fmaf(w3, v3, acc);
  }
  for (; k < end; k++) {
    int s = csr[k];
    acc = fmaf(dn * dis[s], x[(size_t)s * 64 + lane], acc);
  }
  unsigned short h_, l_;
  split_bf(acc, h_, l_);
  zhi[(size_t)node * 64 + lane] = h_;
  zlo[(size_t)node * 64 + lane] = l_;
}

__global__ __launch_bounds__(256) void agg128_kernel(const float* __restrict__ h,
                                                     const float* __restrict__ dis,
                                                     const int* __restrict__ offsets,
                                                     const int* __restrict__ csr,
                                                     unsigned short* __restrict__ zhi,
                                                     unsigned short* __restrict__ zlo) {
  int node = blockIdx.x * 4 + (threadIdx.x >> 6);
  int lane = threadIdx.x & 63;
  float dn = dis[node];
  float sn = dn * dn;
  const float* hr = h + (size_t)node * 128;
  float a0 = hr[lane] * sn;
  float a1 = hr[lane + 64] * sn;
  int beg = offsets[node], end = offsets[node + 1];
  int k = beg;
  for (; k + 4 <= end; k += 4) {
    int s0 = csr[k], s1 = csr[k + 1], s2 = csr[k + 2], s3 = csr[k + 3];
    float w0 = dn * dis[s0], w1 = dn * dis[s1], w2 = dn * dis[s2], w3 = dn * dis[s3];
    const float* p0 = h + (size_t)s0 * 128;
    const float* p1 = h + (size_t)s1 * 128;
    const float* p2 = h + (size_t)s2 * 128;
    const float* p3 = h + (size_t)s3 * 128;
    float u0 = p0[lane], d0 = p0[lane + 64];
    float u1 = p1[lane], d1 = p1[lane + 64];
    float u2 = p2[lane], d2 = p2[lane + 64];
    float u3 = p3[lane], d3 = p3[lane + 64];
    a0 = fmaf(w0, u0, a0); a1 = fmaf(w0, d0, a1);
    a0 = fmaf(w1, u1, a0); a1 = fmaf(w1, d1, a1);
    a0 = fmaf(w2, u2, a0); a1 = fmaf(w2, d2, a1);
    a0 = fmaf(w3, u3, a0); a1 = fmaf(w3, d3, a1);
  }
  for (; k < end; k++) {
    int s = csr[k];
    float w = dn * dis[s];
    const float* hs = h + (size_t)s * 128;
    a0 = fmaf(w, hs[lane], a0);
    a1 = fmaf(w, hs[lane + 64], a1);
  }
  unsigned short h0, l0, h1, l1;
  split_bf(a0, h0, l0);
  split_bf(a1, h1, l1);
  zhi[(size_t)node * 128 + lane] = h0;
  zlo[(size_t)node * 128 + lane] = l0;
  zhi[(size_t)node * 128 + lane + 64] = h1;
  zlo[(size_t)node * 128 + lane + 64] = l1;
}

// ---------------- weight prep: fp32 W -> bf16 hi/lo in b-fragment layout ----------------
template <bool TRANS>
__global__ __launch_bounds__(256) void wprep_kernel(const float* __restrict__ W, int K, int O,
                                                    unsigned short* __restrict__ hi,
                                                    unsigned short* __restrict__ lo) {
  int idx = blockIdx.x * 256 + threadIdx.x;
  int KC = K / 32;
  int total = (O / 16) * KC * 64;
  if (idx >= total) return;
  int lane = idx & 63;
  int rest = idx >> 6;
  int kc = rest % KC;
  int nt = rest / KC;
  int n = nt * 16 + (lane & 15);
  int kb = kc * 32 + (lane >> 4) * 8;
  unsigned short* hp = hi + (size_t)idx * 8;
  unsigned short* lp = lo + (size_t)idx * 8;
#pragma unroll
  for (int j = 0; j < 8; j++) {
    int k = kb + j;
    float v = TRANS ? W[(size_t)n * K + k] : W[(size_t)k * O + n];
    unsigned short h_, l_;
    split_bf(v, h_, l_);
    hp[j] = h_;
    lp[j] = l_;
  }
}

// ---------------- MFMA GEMM ----------------
// SPLIT_OUT: write hi/lo bf16. GROUPED: single output buffer, per-row stride 2*O u16,
// organized as (O/32) groups of 64 u16: [32 hi][32 lo] — keeps hi+lo of a 32-value
// head-slice in ONE 128B cache line for the attention kernel's staged reads.
template <int K, int O, bool DOBN, bool DORELU, bool SPLIT_OUT, bool GROUPED>
__global__ __launch_bounds__(256) void gemm_mfma(
    const unsigned short* __restrict__ Ahi, const unsigned short* __restrict__ Alo,
    const unsigned short* __restrict__ Whi, const unsigned short* __restrict__ Wlo,
    const float* __restrict__ bias,
    const float* __restrict__ gamma, const float* __restrict__ beta,
    const float* __restrict__ mean, const float* __restrict__ var,
    float* __restrict__ Cf, unsigned short* __restrict__ Chi,
    unsigned short* __restrict__ Clo) {
  constexpr int KC = K / 32;
  int wave = threadIdx.x >> 6;
  int lane = threadIdx.x & 63;
  int m0 = blockIdx.x * 128 + wave * 32;
  int o0 = blockIdx.y * 128;
  int mrow = lane & 15;
  int kseg = (lane >> 4) * 8;

  f32x4 acc[2][8];
#pragma unroll
  for (int mt = 0; mt < 2; mt++)
#pragma unroll
    for (int nt = 0; nt < 8; nt++) acc[mt][nt] = (f32x4)0.0f;

#pragma unroll
  for (int kc = 0; kc < KC; kc++) {
    bf16x8 ah[2], al[2];
#pragma unroll
    for (int mt = 0; mt < 2; mt++) {
      size_t aoff = (size_t)(m0 + mt * 16 + mrow) * K + kc * 32 + kseg;
      ah[mt] = *(const bf16x8*)(Ahi + aoff);
      al[mt] = *(const bf16x8*)(Alo + aoff);
    }
#pragma unroll
    for (int nt = 0; nt < 8; nt++) {
      size_t foff = (((size_t)(blockIdx.y * 8 + nt) * KC + kc) * 64 + lane) * 8;
      bf16x8 bh = *(const bf16x8*)(Whi + foff);
      bf16x8 bl = *(const bf16x8*)(Wlo + foff);
#pragma unroll
      for (int mt = 0; mt < 2; mt++) {
        acc[mt][nt] = __builtin_amdgcn_mfma_f32_16x16x32_bf16(ah[mt], bh, acc[mt][nt], 0, 0, 0);
        acc[mt][nt] = __builtin_amdgcn_mfma_f32_16x16x32_bf16(ah[mt], bl, acc[mt][nt], 0, 0, 0);
        acc[mt][nt] = __builtin_amdgcn_mfma_f32_16x16x32_bf16(al[mt], bh, acc[mt][nt], 0, 0, 0);
        acc[mt][nt] = __builtin_amdgcn_mfma_f32_16x16x32_bf16(al[mt], bl, acc[mt][nt], 0, 0, 0);
      }
    }
  }

  int ccol = lane & 15;
  int crow0 = (lane >> 4) * 4;
#pragma unroll
  for (int nt = 0; nt < 8; nt++) {
    int c = o0 + nt * 16 + ccol;
    float sc, cb;
    float b = bias[c];
    if (DOBN) {
      sc = gamma[c] * rsqrtf(var[c] + BN_EPS);
      cb = (b - mean[c]) * sc + beta[c];
    } else {
      sc = 1.0f;
      cb = b;
    }
#pragma unroll
    for (int mt = 0; mt < 2; mt++) {
#pragma unroll
      for (int r = 0; r < 4; r++) {
        float v = fmaf(acc[mt][nt][r], sc, cb);
        if (DORELU) v = fmaxf(v, 0.0f);
        size_t row = (size_t)(m0 + mt * 16 + crow0 + r);
        if (SPLIT_OUT) {
          unsigned short h_, l_;
          split_bf(v, h_, l_);
          if (GROUPED) {
            size_t base = row * (size_t)(2 * O) + (size_t)(((c >> 5) << 6) + (c & 31));
            Chi[base] = h_;
            Chi[base + 32] = l_;
          } else {
            Chi[row * O + c] = h_;
            Clo[row * O + c] = l_;
          }
        } else {
          Cf[row * O + c] = v;
        }
      }
    }
  }
}

// ---------------- key-norm max per (graph, head), grouped split input ----------------
__global__ __launch_bounds__(256) void knorm_kernel(const unsigned short* __restrict__ qvs,
                                                    float* __restrict__ kmax2) {
  int g = blockIdx.x >> 2;
  int h = blockIdx.x & 3;
  size_t gbase = (size_t)g * NPG;
  float best = 0.0f;
#pragma unroll
  for (int r = 0; r < 2; r++) {
    int j = r * 256 + threadIdx.x;
    size_t base = (gbase + j) * 768 + (size_t)(4 + h) * 64;  // K group for head h
    float s = 0.0f;
#pragma unroll
    for (int i = 0; i < 4; i++) {
      u16x8 hh = *(const u16x8*)(qvs + base + i * 8);
      u16x8 ll = *(const u16x8*)(qvs + base + 32 + i * 8);
#pragma unroll
      for (int jj = 0; jj < 8; jj++) {
        float v = bf2f(hh[jj]) + bf2f(ll[jj]);
        s = fmaf(v, v, s);
      }
    }
    best = fmaxf(best, s);
  }
#pragma unroll
  for (int off = 32; off >= 1; off >>= 1)
    best = fmaxf(best, __shfl_xor(best, off, 64));
  __shared__ float red[4];
  int wave = threadIdx.x >> 6;
  if ((threadIdx.x & 63) == 0) red[wave] = best;
  __syncthreads();
  if (threadIdx.x == 0) {
    float m = fmaxf(fmaxf(red[0], red[1]), fmaxf(red[2], red[3]));
    kmax2[blockIdx.x] = m;
  }
}

// ---------------- attention via MFMA (flash-style, single pass, C-S bound) --------------
// grid: 1024 blocks = (graph, head, half), XCD-swizzled so one graph's 8 blocks land on
// one XCD (shared K/V lines L2-hit; partial C-line writes from the 4 heads merge).
// block 256 thr / 4 waves; wave owns 64 queries. QKV in GROUPED split layout:
// node row = 768 u16, 12 groups of [32 hi][32 lo].
// K/V is DOUBLE-BUFFERED in LDS with ONE barrier per chunk:
//   iter c: issue global loads for c+1 -> compute from buf[p] -> ds_write c+1 into
//   buf[p^1] -> barrier. The vmcnt wait for the loads sits after the compute phase,
//   so HBM/L2 latency hides under ~60 MFMAs + softmax (T14), and hipcc's
//   vmcnt(0)-before-s_barrier drain sees already-consumed loads.
__global__ __launch_bounds__(256, 2) void attn_mfma_kernel(
    const unsigned short* __restrict__ qvs, const float* __restrict__ kmax2,
    unsigned short* __restrict__ ohi, unsigned short* __restrict__ olo) {
  // XCD swizzle: HW assigns XCD ~ blockIdx%8; remap so one graph's 8 work items
  // share an XCD. 1024 = 8*128 exactly (bijective).
  int wb = ((blockIdx.x & 7) << 7) | (blockIdx.x >> 3);
  int g = wb >> 3;
  int h = (wb >> 1) & 3;
  int half = wb & 1;
  int t = threadIdx.x;
  int wave = t >> 6;
  int lane = t & 63;
  int quad = lane >> 4;
  int l15 = lane & 15;
  size_t gbase = (size_t)g * NPG;
  int qb = half * 256 + wave * 64;

  const float cf = 0.17677669529663687f * 1.4426950408889634f;  // scale*log2(e)

  __shared__ unsigned short Kh[2][32][40] __attribute__((aligned(16)));
  __shared__ unsigned short Kl[2][32][40] __attribute__((aligned(16)));
  __shared__ unsigned short Vh[2][33][40] __attribute__((aligned(16)));  // row 32 = ones
  __shared__ unsigned short Vl[2][33][40] __attribute__((aligned(16)));
  __shared__ char wbuf[4][10240] __attribute__((aligned(16)));  // per-wave P / O-transpose

  unsigned short* Ph = (unsigned short*)wbuf[wave];        // [64][40] bf16
  unsigned short* Pl = Ph + 64 * 40;                       // [64][40] bf16
  float* Ot = (float*)wbuf[wave];                          // [64][36] f32 (epilogue/qn)

  // ---- Q fragments: direct pre-split loads + |q|^2 (reconstructed = what MFMA sees) ----
  bf16x8 qh[4], ql[4];
  float qn2p[4];
#pragma unroll
  for (int mt = 0; mt < 4; mt++) {
    size_t qoff = (gbase + qb + mt * 16 + l15) * 768 + (size_t)h * 64 + quad * 8;
    u16x8 hh = *(const u16x8*)(qvs + qoff);
    u16x8 ll = *(const u16x8*)(qvs + qoff + 32);
    qh[mt] = __builtin_bit_cast(bf16x8, hh);
    ql[mt] = __builtin_bit_cast(bf16x8, ll);
    float s = 0.0f;
#pragma unroll
    for (int j = 0; j < 8; j++) {
      float v = bf2f(hh[j]) + bf2f(ll[j]);
      s = fmaf(v, v, s);
    }
    s += __shfl_xor(s, 16);
    s += __shfl_xor(s, 32);
    qn2p[mt] = s;  // full |q|^2 for query mt*16 + l15
  }
  // exchange |q|^2 so each lane gets the bound for its C-layout rows
  if (quad == 0) {
#pragma unroll
    for (int mt = 0; mt < 4; mt++) Ot[mt * 16 + l15] = qn2p[mt];
  }
  float km2 = kmax2[g * 4 + h];
  float Mq[4][4];
#pragma unroll
  for (int mt = 0; mt < 4; mt++)
#pragma unroll
    for (int r = 0; r < 4; r++)
      Mq[mt][r] = cf * sqrtf(Ot[mt * 16 + quad * 4 + r] * km2);

  f32x4 Oa[4][3];
#pragma unroll
  for (int mt = 0; mt < 4; mt++)
#pragma unroll
    for (int nt = 0; nt < 3; nt++) Oa[mt][nt] = (f32x4)0.0f;

  // ones rows for the l-column (dv=32), both buffers, once: threads 64-71
  if (t >= 64 && t < 72) {
    int u = t - 64;
    int bsel = u >> 2;
    int i = u & 3;
    u16x8 ones;
#pragma unroll
    for (int j = 0; j < 8; j++) ones[j] = 0x3F80;
    *(u16x8*)&Vh[bsel][32][i * 8] = ones;
  }

  // staging roles: threads 128-255 stage K (32 keys x 4 dim-segments);
  // threads 0-63 stage V^T (8 key-blocks x 8 dim-blocks)
  bool isK = (t >= 128);
  bool isV = (t < 64);
  u16x8 kreg_h, kreg_l;
  ushort4 vreg_h[4], vreg_l[4];
  int kkey = 0, kds = 0, vkeyb = 0, vdvb = 0;
  if (isK) {
    int t2 = t - 128;
    kkey = t2 >> 2;
    kds = (t2 & 3) * 8;
  } else if (isV) {
    vkeyb = (t & 7) * 4;
    vdvb = (t >> 3) * 4;
  }

  auto load_chunk = [&](int c) {
    if (isK) {
      size_t ko = (gbase + (size_t)(c * 32 + kkey)) * 768 + (size_t)(4 + h) * 64 + kds;
      kreg_h = *(const u16x8*)(qvs + ko);
      kreg_l = *(const u16x8*)(qvs + ko + 32);
    } else if (isV) {
#pragma unroll
      for (int r = 0; r < 4; r++) {
        size_t vo = (gbase + (size_t)(c * 32 + vkeyb + r)) * 768 + (size_t)(8 + h) * 64 + vdvb;
        vreg_h[r] = *(const ushort4*)(qvs + vo);
        vreg_l[r] = *(const ushort4*)(qvs + vo + 32);
      }
    }
  };

  auto stage_chunk = [&](int bsel) {
    if (isK) {
      *(u16x8*)&Kh[bsel][kkey][kds] = kreg_h;
      *(u16x8*)&Kl[bsel][kkey][kds] = kreg_l;
    } else if (isV) {
      unsigned short ha[4][4], la[4][4];
#pragma unroll
      for (int r = 0; r < 4; r++) {
        *(ushort4*)&ha[r][0] = vreg_h[r];
        *(ushort4*)&la[r][0] = vreg_l[r];
      }
#pragma unroll
      for (int c2 = 0; c2 < 4; c2++) {
        ushort4 hv, lv;
        hv.x = ha[0][c2]; hv.y = ha[1][c2]; hv.z = ha[2][c2]; hv.w = ha[3][c2];
        lv.x = la[0][c2]; lv.y = la[1][c2]; lv.z = la[2][c2]; lv.w = la[3][c2];
        *(ushort4*)&Vh[bsel][vdvb + c2][vkeyb] = hv;
        *(ushort4*)&Vl[bsel][vdvb + c2][vkeyb] = lv;
      }
    }
  };

  // prologue: chunk 0 into buf 0
  load_chunk(0);
  stage_chunk(0);
  __syncthreads();

  int p = 0;
  for (int c = 0; c < 16; c++) {
    // ---- issue next chunk's loads first: latency hides under the compute below ----
    if (c < 15) load_chunk(c + 1);

    // ---- QK^T -> S -> P (scale folded into fma; cheap trunc-split; store to LDS) ----
#pragma unroll
    for (int nt = 0; nt < 2; nt++) {
      bf16x8 bkh = *(const bf16x8*)&Kh[p][nt * 16 + l15][quad * 8];
      bf16x8 bkl = *(const bf16x8*)&Kl[p][nt * 16 + l15][quad * 8];
#pragma unroll
      for (int mt = 0; mt < 4; mt++) {
        f32x4 S = (f32x4)0.0f;
        S = __builtin_amdgcn_mfma_f32_16x16x32_bf16(qh[mt], bkh, S, 0, 0, 0);
        S = __builtin_amdgcn_mfma_f32_16x16x32_bf16(qh[mt], bkl, S, 0, 0, 0);
        S = __builtin_amdgcn_mfma_f32_16x16x32_bf16(ql[mt], bkh, S, 0, 0, 0);
        S = __builtin_amdgcn_mfma_f32_16x16x32_bf16(ql[mt], bkl, S, 0, 0, 0);
#pragma unroll
        for (int r = 0; r < 4; r++) {
          float pexp = __builtin_exp2f(fmaf(S[r], cf, -Mq[mt][r]));
          unsigned short hi_, lo_;
          split_bf_fast(pexp, hi_, lo_);
          int row = mt * 16 + quad * 4 + r;
          Ph[row * 40 + nt * 16 + l15] = hi_;
          Pl[row * 40 + nt * 16 + l15] = lo_;
        }
      }
    }
    // ---- PV: P A-frags x V^T B-frags ----
    bf16x8 pah[4], pal[4];
#pragma unroll
    for (int mt = 0; mt < 4; mt++) {
      pah[mt] = *(const bf16x8*)&Ph[(mt * 16 + l15) * 40 + quad * 8];
      pal[mt] = *(const bf16x8*)&Pl[(mt * 16 + l15) * 40 + quad * 8];
    }
#pragma unroll
    for (int nt = 0; nt < 3; nt++) {
      bf16x8 bvh = *(const bf16x8*)&Vh[p][nt * 16 + l15][quad * 8];
      if (nt < 2) {
        bf16x8 bvl = *(const bf16x8*)&Vl[p][nt * 16 + l15][quad * 8];
#pragma unroll
        for (int mt = 0; mt < 4; mt++) {
          Oa[mt][nt] = __builtin_amdgcn_mfma_f32_16x16x32_bf16(pah[mt], bvh, Oa[mt][nt], 0, 0, 0);
          Oa[mt][nt] = __builtin_amdgcn_mfma_f32_16x16x32_bf16(pah[mt], bvl, Oa[mt][nt], 0, 0, 0);
          Oa[mt][nt] = __builtin_amdgcn_mfma_f32_16x16x32_bf16(pal[mt], bvh, Oa[mt][nt], 0, 0, 0);
        }
      } else {
#pragma unroll
        for (int mt = 0; mt < 4; mt++) {
          Oa[mt][nt] = __builtin_amdgcn_mfma_f32_16x16x32_bf16(pah[mt], bvh, Oa[mt][nt], 0, 0, 0);
          Oa[mt][nt] = __builtin_amdgcn_mfma_f32_16x16x32_bf16(pal[mt], bvh, Oa[mt][nt], 0, 0, 0);
        }
      }
    }

    // ---- write prefetched chunk c+1 into the other buffer, then single barrier ----
    if (c < 15) stage_chunk(p ^ 1);
    __syncthreads();
    p ^= 1;
  }

  // ---- epilogue: transpose O through per-wave LDS, normalize, split-bf16 store ----
  // (per-wave buffer; wave-lockstep ds ordering makes this barrier-free)
#pragma unroll
  for (int mt = 0; mt < 4; mt++) {
#pragma unroll
    for (int r = 0; r < 4; r++) {
      int row = mt * 16 + quad * 4 + r;
      Ot[row * 36 + l15] = Oa[mt][0][r];
      Ot[row * 36 + 16 + l15] = Oa[mt][1][r];
      if (l15 == 0) Ot[row * 36 + 32] = Oa[mt][2][r];  // l = ones-column
    }
  }
  {
    int row = lane;  // wave's query row
    float inv = 1.0f / Ot[row * 36 + 32];
    size_t node = gbase + qb + row;
    u16x8 vh, vl;
#pragma unroll
    for (int seg = 0; seg < 4; seg++) {
#pragma unroll
      for (int j = 0; j < 8; j++) {
        unsigned short hi_, lo_;
        split_bf_fast(Ot[row * 36 + seg * 8 + j] * inv, hi_, lo_);
        vh[j] = hi_;
        vl[j] = lo_;
      }
      *(u16x8*)(ohi + node * 128 + h * 32 + seg * 8) = vh;
      *(u16x8*)(olo + node * 128 + h * 32 + seg * 8) = vl;
    }
  }
}

// ---------------- mean pool: 4 partial blocks per graph + atomic combine ----------------
__global__ __launch_bounds__(128) void pool_kernel(const float* __restrict__ fin,
                                                   float* __restrict__ emb) {
  int g = blockIdx.x >> 2;
  int q = blockIdx.x & 3;
  int c = threadIdx.x;
  const float* p = fin + ((size_t)g * NPG + (size_t)q * 128) * HID + c;
  float s = 0.0f;
#pragma unroll 4
  for (int i = 0; i < 128; i++) s += p[(size_t)i * HID];
  atomicAdd(&emb[g * HID + c], s * (1.0f / NPG));
}

extern "C" void kernel_launch(void* const* d_in, const int* in_sizes, int n_in,
                              void* d_out, int out_size, void* d_ws, size_t ws_size,
                              hipStream_t stream) {
  (void)in_sizes; (void)n_in; (void)out_size; (void)ws_size;
  const float* x          = (const float*)d_in[0];
  const float* W0         = (const float*)d_in[1];
  const float* b0         = (const float*)d_in[2];
  const float* Wh         = (const float*)d_in[3];
  const float* bh         = (const float*)d_in[4];
  const float* bn_gamma   = (const float*)d_in[5];
  const float* bn_beta    = (const float*)d_in[6];
  const float* bn_mean    = (const float*)d_in[7];
  const float* bn_var     = (const float*)d_in[8];
  const float* attn_in_w  = (const float*)d_in[9];
  const float* attn_in_b  = (const float*)d_in[10];
  const float* attn_out_w = (const float*)d_in[11];
  const float* attn_out_b = (const float*)d_in[12];
  const int* edge_index   = (const int*)d_in[13];
  const int* src = edge_index;
  const int* dst = edge_index + N_EDGES;

  char* ws = (char*)d_ws;
  size_t off = 0;
  auto alloc = [&](size_t bytes) -> void* {
    void* p = ws + off;
    off += (bytes + 255) & ~(size_t)255;
    return p;
  };
  int*   deg     = (int*)alloc((size_t)N_NODES * 4);
  int*   offsets = (int*)alloc((size_t)(N_NODES + 1) * 4);
  int*   cursor  = (int*)alloc((size_t)N_NODES * 4);
  int*   csr     = (int*)alloc((size_t)N_EDGES * 4);
  float* dis     = (float*)alloc((size_t)N_NODES * 4);
  float* bufA    = (float*)alloc((size_t)N_NODES * HID * 4);   // h fp32; later f_hi/f_lo
  unsigned short* zhi = (unsigned short*)alloc((size_t)N_NODES * HID * 2);  // also o_hi
  unsigned short* zlo = (unsigned short*)alloc((size_t)N_NODES * HID * 2);  // also o_lo
  unsigned short* qvs = (unsigned short*)alloc((size_t)N_NODES * 768 * 2);  // qkv grouped hi/lo
  float* kmax2   = (float*)alloc((size_t)N_GRAPHS * 4 * 4);
  unsigned short* w0h = (unsigned short*)alloc(8192 * 2);
  unsigned short* w0l = (unsigned short*)alloc(8192 * 2);
  unsigned short* whh[3], *whl[3];
  for (int i = 0; i < 3; i++) {
    whh[i] = (unsigned short*)alloc(16384 * 2);
    whl[i] = (unsigned short*)alloc(16384 * 2);
  }
  unsigned short* wqh = (unsigned short*)alloc(49152 * 2);
  unsigned short* wql = (unsigned short*)alloc(49152 * 2);
  unsigned short* woh = (unsigned short*)alloc(16384 * 2);
  unsigned short* wol = (unsigned short*)alloc(16384 * 2);

  unsigned short* fhi = (unsigned short*)bufA;
  unsigned short* flo = fhi + (size_t)N_NODES * HID;

  float* fin = (float*)d_out;                       // [N, HID]
  float* emb = fin + (size_t)N_NODES * HID;         // [G, HID]

  hipMemsetAsync(deg, 0, (size_t)N_NODES * 4, stream);
  hipMemsetAsync(emb, 0, (size_t)N_GRAPHS * HID * 4, stream);
  hist_kernel<<<N_EDGES / 256, 256, 0, stream>>>(dst, deg);
  dis_kernel<<<N_NODES / 256, 256, 0, stream>>>(deg, dis);
  scan_kernel<<<1, 1024, 0, stream>>>(deg, offsets, cursor);
  fill_kernel<<<N_EDGES / 256, 256, 0, stream>>>(src, dst, cursor, csr);

  wprep_kernel<false><<<4, 256, 0, stream>>>(W0, 64, 128, w0h, w0l);
  for (int i = 0; i < 3; i++)
    wprep_kernel<false><<<8, 256, 0, stream>>>(Wh + (size_t)i * HID * HID, 128, 128,
                                               whh[i], whl[i]);
  wprep_kernel<true><<<24, 256, 0, stream>>>(attn_in_w, 128, 384, wqh, wql);
  wprep_kernel<true><<<8, 256, 0, stream>>>(attn_out_w, 128, 128, woh, wol);

  dim3 ggrid(N_NODES / 128, 1);
  agg64_kernel<<<N_NODES / 4, 256, 0, stream>>>(x, dis, offsets, csr, zhi, zlo);
  gemm_mfma<64, 128, true, true, false, false><<<ggrid, 256, 0, stream>>>(
      zhi, zlo, w0h, w0l, b0, bn_gamma, bn_beta, bn_mean, bn_var, bufA, nullptr, nullptr);
  for (int L = 0; L < 2; L++) {
    agg128_kernel<<<N_NODES / 4, 256, 0, stream>>>(bufA, dis, offsets, csr, zhi, zlo);
    gemm_mfma<128, 128, true, true, false, false><<<ggrid, 256, 0, stream>>>(
        zhi, zlo, whh[L], whl[L], bh + (size_t)L * HID,
        bn_gamma + (size_t)(L + 1) * HID, bn_beta + (size_t)(L + 1) * HID,
        bn_mean + (size_t)(L + 1) * HID, bn_var + (size_t)(L + 1) * HID,
        bufA, nullptr, nullptr);
  }
  agg128_kernel<<<N_NODES / 4, 256, 0, stream>>>(bufA, dis, offsets, csr, zhi, zlo);
  gemm_mfma<128, 128, true, true, true, false><<<ggrid, 256, 0, stream>>>(
      zhi, zlo, whh[2], whl[2], bh + (size_t)2 * HID,
      bn_gamma + (size_t)3 * HID, bn_beta + (size_t)3 * HID,
      bn_mean + (size_t)3 * HID, bn_var + (size_t)3 * HID,
      nullptr, fhi, flo);
  dim3 qgrid(N_NODES / 128, 3);
  gemm_mfma<128, 384, false, false, true, true><<<qgrid, 256, 0, stream>>>(
      fhi, flo, wqh, wql, attn_in_b, nullptr, nullptr, nullptr, nullptr,
      nullptr, qvs, nullptr);
  knorm_kernel<<<N_GRAPHS * 4, 256, 0, stream>>>(qvs, kmax2);
  attn_mfma_kernel<<<N_GRAPHS * 4 * 2, 256, 0, stream>>>(qvs, kmax2, zhi, zlo);
  gemm_mfma<128, 128, false, false, false, false><<<ggrid, 256, 0, stream>>>(
      zhi, zlo, woh, wol, attn_out_b, nullptr, nullptr, nullptr, nullptr,
      fin, nullptr, nullptr);
  pool_kernel<<<N_GRAPHS * 4, 128, 0, stream>>>(fin, emb);
}